// Round 2
// baseline (533.207 us; speedup 1.0000x reference)
//
#include <hip/hip_runtime.h>

// DHG layer, fused single kernel.
// Mapping: one wave (64 lanes) per id. Members of 4 hyperedges (=64) map 1:1 to
// lanes for the vertex-conv MLP (weights become SGPR scalars -> pure v_fmac loop).
// Softmax over 16-lane groups via shfl_xor. Weighted pooling re-reads rows
// coalesced (lane = column pair), hitting L1/L2 (just fetched). he[8][128] kept in
// registers (lane=column) + mirrored to a small LDS slice for the edge-conv
// reduction, which uses lane=(s, j-quad) with broadcast LDS reads (conflict-free,
// pad 129: s8*129 % 32 == s8). FC uses lane = output-column-pair, fc_w L2-hot.

constexpr int S_   = 8;
constexpr int K_   = 16;
constexpr int D_   = 128;
constexpr int HVC  = 9;
constexpr int HEC  = 32;

__device__ __forceinline__ float rl_f(float v, int lane) {
    return __int_as_float(__builtin_amdgcn_readlane(__float_as_int(v), lane));
}

__global__ __launch_bounds__(256, 4)
void dhg_fused(const int* __restrict__ ids,
               const float* __restrict__ feats,
               const int* __restrict__ adj,
               const float* __restrict__ vc_w1, const float* __restrict__ vc_b1,
               const float* __restrict__ vc_w2, const float* __restrict__ vc_b2,
               const float* __restrict__ ec_w1, const float* __restrict__ ec_b1,
               const float* __restrict__ ec_w2, const float* __restrict__ ec_b2,
               const float* __restrict__ fc_w,  const float* __restrict__ fc_b,
               float* __restrict__ out, int n_ids)
{
    __shared__ float he_lds[4][S_ * 129];  // per-wave slice; pad 129 => broadcast reads conflict-free
    __shared__ float x_lds[4][D_];

    const int wave = threadIdx.x >> 6;
    const int lane = threadIdx.x & 63;
    int wid = blockIdx.x * 4 + wave;
    if (wid >= n_ids) wid = n_ids - 1;   // n_ids divisible by 4 in practice; clamp is safe

    const int node = ids[wid];
    const int* arow = adj + (unsigned)(node * (S_ * K_));   // 128 contiguous ints
    const int miA = arow[lane];        // member = lane        (hyperedges 0..3)
    const int miB = arow[lane + 64];   // member = lane + 64   (hyperedges 4..7)

    const float vb2 = vc_b2[0];

    float he_lo[S_], he_hi[S_];        // he[s][2*lane], he[s][2*lane+1]

    #pragma unroll
    for (int g = 0; g < 2; ++g) {
        // ---- vertex-conv MLP: each lane owns one member row ----
        const int mi = g ? miB : miA;
        const float* rp = feats + (size_t)((unsigned)mi * (unsigned)D_);
        float h[HVC];
        #pragma unroll
        for (int j = 0; j < HVC; ++j) h[j] = vc_b1[j];

        #pragma unroll 4
        for (int i = 0; i < D_ / 4; ++i) {
            const float4 gv = *(const float4*)(rp + 4 * i);
            const float gc[4] = {gv.x, gv.y, gv.z, gv.w};
            #pragma unroll
            for (int c = 0; c < 4; ++c) {
                #pragma unroll
                for (int j = 0; j < HVC; ++j)   // weight is wave-uniform -> SGPR operand
                    h[j] = fmaf(gc[c], vc_w1[(4 * i + c) * HVC + j], h[j]);
            }
        }
        float sc = vb2;
        #pragma unroll
        for (int j = 0; j < HVC; ++j) sc = fmaf(fmaxf(h[j], 0.0f), vc_w2[j], sc);

        // ---- softmax over the 16 members of this lane's hyperedge ----
        float mx = sc;
        #pragma unroll
        for (int m = 1; m <= 8; m <<= 1) mx = fmaxf(mx, __shfl_xor(mx, m));
        const float e = __expf(sc - mx);
        float z = e;
        #pragma unroll
        for (int m = 1; m <= 8; m <<= 1) z += __shfl_xor(z, m);

        // ---- weighted pooling: lane = column pair, coalesced re-read (L2/L3-hot) ----
        #pragma unroll
        for (int sl = 0; sl < 4; ++sl) {
            const int s = g * 4 + sl;
            float alo = 0.0f, ahi = 0.0f;
            #pragma unroll
            for (int k = 0; k < K_; ++k) {
                const int src = sl * 16 + k;
                const float ek = rl_f(e, src);                                   // SGPR scalar
                const int mik = __builtin_amdgcn_readlane(g ? miB : miA, src);   // SGPR row index
                const float2 fv = *(const float2*)(feats + (size_t)((unsigned)mik * (unsigned)D_) + 2 * lane);
                alo = fmaf(ek, fv.x, alo);
                ahi = fmaf(ek, fv.y, ahi);
            }
            const float invz = 1.0f / rl_f(z, sl * 16);
            he_lo[s] = alo * invz;
            he_hi[s] = ahi * invz;
            he_lds[wave][s * 129 + 2 * lane]     = he_lo[s];
            he_lds[wave][s * 129 + 2 * lane + 1] = he_hi[s];
        }
    }

    __syncthreads();

    // ---- edge conv: lane = (jg = lane>>3, s8 = lane&7); j in [4*jg, 4*jg+4) ----
    const int s8 = lane & 7;
    const int jg = lane >> 3;
    const float* hrow = &he_lds[wave][s8 * 129];
    float a0 = 0.0f, a1 = 0.0f, a2 = 0.0f, a3 = 0.0f;
    #pragma unroll 4
    for (int d = 0; d < D_; ++d) {
        const float hv = hrow[d];                                     // LDS broadcast, conflict-free
        const float4 wv = *(const float4*)(ec_w1 + d * HEC + 4 * jg); // L1-hot (16 KB table)
        a0 = fmaf(hv, wv.x, a0);
        a1 = fmaf(hv, wv.y, a1);
        a2 = fmaf(hv, wv.z, a2);
        a3 = fmaf(hv, wv.w, a3);
    }
    const float4 b4  = *(const float4*)(ec_b1 + 4 * jg);
    const float4 w24 = *(const float4*)(ec_w2 + 4 * jg);
    float p = 0.0f;
    p = fmaf(fmaxf(a0 + b4.x, 0.0f), w24.x, p);
    p = fmaf(fmaxf(a1 + b4.y, 0.0f), w24.y, p);
    p = fmaf(fmaxf(a2 + b4.z, 0.0f), w24.z, p);
    p = fmaf(fmaxf(a3 + b4.w, 0.0f), w24.w, p);
    #pragma unroll
    for (int m = 8; m <= 32; m <<= 1) p += __shfl_xor(p, m);   // reduce over jg (bits 3..5)
    const float sc2 = p + ec_b2[0];

    // softmax over 8 hyperedges (lane bits 0..2)
    float mx2 = sc2;
    #pragma unroll
    for (int m = 1; m <= 4; m <<= 1) mx2 = fmaxf(mx2, __shfl_xor(mx2, m));
    const float e2 = __expf(sc2 - mx2);
    float z2 = e2;
    #pragma unroll
    for (int m = 1; m <= 4; m <<= 1) z2 += __shfl_xor(z2, m);
    const float p2 = e2 / z2;   // lanes 0..7 hold softmax weights for s=0..7

    // ---- x = sum_s p2[s] * he[s][:], lane = column pair (he in registers) ----
    float x_lo = 0.0f, x_hi = 0.0f;
    #pragma unroll
    for (int s = 0; s < S_; ++s) {
        const float ps = rl_f(p2, s);
        x_lo = fmaf(ps, he_lo[s], x_lo);
        x_hi = fmaf(ps, he_hi[s], x_hi);
    }
    x_lds[wave][2 * lane]     = x_lo;
    x_lds[wave][2 * lane + 1] = x_hi;

    __syncthreads();

    // ---- FC 128x128 + ReLU: lane = output column pair, fc_w L2-hot ----
    const float* xr = x_lds[wave];
    float2 acc = *(const float2*)(fc_b + 2 * lane);
    #pragma unroll 8
    for (int d = 0; d < D_; ++d) {
        const float xv = xr[d];                                       // LDS broadcast
        const float2 wv = *(const float2*)(fc_w + d * D_ + 2 * lane);
        acc.x = fmaf(xv, wv.x, acc.x);
        acc.y = fmaf(xv, wv.y, acc.y);
    }
    float2 o;
    o.x = fmaxf(acc.x, 0.0f);
    o.y = fmaxf(acc.y, 0.0f);
    *(float2*)(out + (size_t)((unsigned)wid * (unsigned)D_) + 2 * lane) = o;
}

extern "C" void kernel_launch(void* const* d_in, const int* in_sizes, int n_in,
                              void* d_out, int out_size, void* d_ws, size_t ws_size,
                              hipStream_t stream)
{
    const int*   ids   = (const int*)d_in[0];
    const float* feats = (const float*)d_in[1];
    const int*   adj   = (const int*)d_in[2];
    const float* vc_w1 = (const float*)d_in[3];
    const float* vc_b1 = (const float*)d_in[4];
    const float* vc_w2 = (const float*)d_in[5];
    const float* vc_b2 = (const float*)d_in[6];
    const float* ec_w1 = (const float*)d_in[7];
    const float* ec_b1 = (const float*)d_in[8];
    const float* ec_w2 = (const float*)d_in[9];
    const float* ec_b2 = (const float*)d_in[10];
    const float* fc_w  = (const float*)d_in[11];
    const float* fc_b  = (const float*)d_in[12];
    float* out = (float*)d_out;

    const int n_ids = in_sizes[0];
    const int blocks = (n_ids + 3) / 4;   // 4 ids (waves) per 256-thread block
    dhg_fused<<<blocks, 256, 0, stream>>>(ids, feats, adj,
                                          vc_w1, vc_b1, vc_w2, vc_b2,
                                          ec_w1, ec_b1, ec_w2, ec_b2,
                                          fc_w, fc_b, out, n_ids);
}

// Round 4
// 385.193 us; speedup vs baseline: 1.3843x; 1.3843x over previous
//
#include <hip/hip_runtime.h>

// DHG layer, two-kernel scheme.
//
// Insight: vertex-conv attention scores depend ONLY on the member feature row
// (score1[n] = MLP1(feats[n])), so they are precomputed for all N_TOTAL nodes
// once per launch (kernel A, ~25 us) instead of being re-derived per (id,s,k)
// reference (2.56M refs over 100K rows). This deletes the per-lane scattered
// 512B row reads of the old pass 1 (half of all gather traffic, ~60% of VALU).
//
// Kernel B: one wave per id. Scores gathered as 4B from a 400KB L2-resident
// table; softmax over 16-lane groups via shfl_xor; weighted pooling does the
// single remaining feats gather: per member one wave-coalesced 512B row read
// (lane = column pair), 16 loads/window hoisted into registers ahead of the
// fmac chain. he[8][128] lives in registers + per-wave LDS mirror (pad 129 ->
// broadcast reads conflict-free). No __syncthreads: every wave touches only
// its own LDS slice; per-wave DS ops execute in order (ISA guarantee) and
// __builtin_amdgcn_wave_barrier() (zero-cost compiler fence) prevents the
// compiler from reordering reads before writes.

constexpr int S_   = 8;
constexpr int K_   = 16;
constexpr int D_   = 128;
constexpr int HVC  = 9;
constexpr int HEC  = 32;

__device__ __forceinline__ float rl_f(float v, int lane) {
    return __int_as_float(__builtin_amdgcn_readlane(__float_as_int(v), lane));
}

// ---- kernel A: score1[n] = MLP1(feats[n]) for all nodes ----
__global__ __launch_bounds__(256)
void dhg_score1(const float* __restrict__ feats,
                const float* __restrict__ vc_w1, const float* __restrict__ vc_b1,
                const float* __restrict__ vc_w2, const float* __restrict__ vc_b2,
                float* __restrict__ score1, int n_total)
{
    const int n = blockIdx.x * 256 + threadIdx.x;
    if (n >= n_total) return;
    const float* rp = feats + (size_t)n * D_;

    float h[HVC];
    #pragma unroll
    for (int j = 0; j < HVC; ++j) h[j] = vc_b1[j];

    #pragma unroll 4
    for (int i = 0; i < D_ / 4; ++i) {
        const float4 gv = *(const float4*)(rp + 4 * i);
        const float gc[4] = {gv.x, gv.y, gv.z, gv.w};
        #pragma unroll
        for (int c = 0; c < 4; ++c) {
            #pragma unroll
            for (int j = 0; j < HVC; ++j)   // weight wave-uniform -> SGPR operand
                h[j] = fmaf(gc[c], vc_w1[(4 * i + c) * HVC + j], h[j]);
        }
    }
    float sc = vc_b2[0];
    #pragma unroll
    for (int j = 0; j < HVC; ++j) sc = fmaf(fmaxf(h[j], 0.0f), vc_w2[j], sc);
    score1[n] = sc;
}

// ---- softmax weight over 16-lane groups: returns e/z for this lane ----
__device__ __forceinline__ float softmax16(float sc) {
    float mx = sc;
    #pragma unroll
    for (int m = 1; m <= 8; m <<= 1) mx = fmaxf(mx, __shfl_xor(mx, m));
    const float e = __expf(sc - mx);
    float z = e;
    #pragma unroll
    for (int m = 1; m <= 8; m <<= 1) z += __shfl_xor(z, m);
    return e / z;
}

// ---- kernel B: main fused layer, one wave per id ----
__global__ __launch_bounds__(128, 4)
void dhg_main(const int* __restrict__ ids,
              const float* __restrict__ feats,
              const int* __restrict__ adj,
              const float* __restrict__ score1,
              const float* __restrict__ ec_w1, const float* __restrict__ ec_b1,
              const float* __restrict__ ec_w2, const float* __restrict__ ec_b2,
              const float* __restrict__ fc_w,  const float* __restrict__ fc_b,
              float* __restrict__ out, int n_ids)
{
    __shared__ float he_lds[2][S_ * 129];  // per-wave slice; pad 129 => broadcast conflict-free
    __shared__ float x_lds[2][D_];

    const int wave = threadIdx.x >> 6;
    const int lane = threadIdx.x & 63;
    int wid = blockIdx.x * 2 + wave;
    if (wid >= n_ids) wid = n_ids - 1;

    const int node = ids[wid];
    const int* arow = adj + (size_t)(unsigned)node * (S_ * K_);
    const int miA = arow[lane];          // hyperedges 0..3, member = lane (s=lane>>4, k=lane&15)
    const int miB = arow[lane + 64];     // hyperedges 4..7

    // gather precomputed scores (400 KB table, L2-resident) + softmax weights
    const float wA = softmax16(score1[miA]);
    const float wB = softmax16(score1[miB]);

    float he_lo[S_], he_hi[S_];          // he[s][2*lane], he[s][2*lane+1]

    #pragma unroll
    for (int g = 0; g < 2; ++g) {
        const int   mi = g ? miB : miA;
        const float w  = g ? wB  : wA;
        #pragma unroll
        for (int sl = 0; sl < 4; ++sl) {
            const int s = g * 4 + sl;
            // hoist all 16 row loads (wave-coalesced 512B rows) before the fmac chain
            float2 fv[K_];
            #pragma unroll
            for (int k = 0; k < K_; ++k) {
                const int mik = __builtin_amdgcn_readlane(mi, sl * 16 + k);  // SGPR row idx
                fv[k] = *(const float2*)(feats + (size_t)(unsigned)mik * D_ + 2 * lane);
            }
            float alo = 0.0f, ahi = 0.0f;
            #pragma unroll
            for (int k = 0; k < K_; ++k) {
                const float wk = rl_f(w, sl * 16 + k);                        // SGPR weight
                alo = fmaf(wk, fv[k].x, alo);
                ahi = fmaf(wk, fv[k].y, ahi);
            }
            he_lo[s] = alo;
            he_hi[s] = ahi;
            he_lds[wave][s * 129 + 2 * lane]     = alo;
            he_lds[wave][s * 129 + 2 * lane + 1] = ahi;
        }
    }

    __builtin_amdgcn_wave_barrier();   // zero-cost fence: keep LDS writes before reads

    // ---- edge conv: lane = (jg = lane>>3, s8 = lane&7); j in [4*jg, 4*jg+4) ----
    // he_lds written/read by this wave only -> per-wave DS in-order suffices.
    const int s8 = lane & 7;
    const int jg = lane >> 3;
    const float* hrow = &he_lds[wave][s8 * 129];
    float a0 = 0.0f, a1 = 0.0f, a2 = 0.0f, a3 = 0.0f;
    #pragma unroll 4
    for (int d = 0; d < D_; ++d) {
        const float hv = hrow[d];                                     // LDS broadcast
        const float4 wv = *(const float4*)(ec_w1 + d * HEC + 4 * jg); // 16 KB, cache-hot
        a0 = fmaf(hv, wv.x, a0);
        a1 = fmaf(hv, wv.y, a1);
        a2 = fmaf(hv, wv.z, a2);
        a3 = fmaf(hv, wv.w, a3);
    }
    const float4 b4  = *(const float4*)(ec_b1 + 4 * jg);
    const float4 w24 = *(const float4*)(ec_w2 + 4 * jg);
    float p = 0.0f;
    p = fmaf(fmaxf(a0 + b4.x, 0.0f), w24.x, p);
    p = fmaf(fmaxf(a1 + b4.y, 0.0f), w24.y, p);
    p = fmaf(fmaxf(a2 + b4.z, 0.0f), w24.z, p);
    p = fmaf(fmaxf(a3 + b4.w, 0.0f), w24.w, p);
    #pragma unroll
    for (int m = 8; m <= 32; m <<= 1) p += __shfl_xor(p, m);   // reduce over jg (bits 3..5)
    const float sc2 = p + ec_b2[0];

    // softmax over 8 hyperedges (lane bits 0..2)
    float mx2 = sc2;
    #pragma unroll
    for (int m = 1; m <= 4; m <<= 1) mx2 = fmaxf(mx2, __shfl_xor(mx2, m));
    const float e2 = __expf(sc2 - mx2);
    float z2 = e2;
    #pragma unroll
    for (int m = 1; m <= 4; m <<= 1) z2 += __shfl_xor(z2, m);
    const float p2 = e2 / z2;   // lanes 0..7 hold weights for s=0..7

    // ---- x = sum_s p2[s] * he[s][:], lane = column pair (he in registers) ----
    float x_lo = 0.0f, x_hi = 0.0f;
    #pragma unroll
    for (int s = 0; s < S_; ++s) {
        const float ps = rl_f(p2, s);
        x_lo = fmaf(ps, he_lo[s], x_lo);
        x_hi = fmaf(ps, he_hi[s], x_hi);
    }
    x_lds[wave][2 * lane]     = x_lo;
    x_lds[wave][2 * lane + 1] = x_hi;

    __builtin_amdgcn_wave_barrier();   // zero-cost fence before cross-lane x_lds reads

    // ---- FC 128x128 + ReLU: lane = output column pair, fc_w L2-hot ----
    const float* xr = x_lds[wave];
    float2 acc = *(const float2*)(fc_b + 2 * lane);
    #pragma unroll 8
    for (int d = 0; d < D_; ++d) {
        const float xv = xr[d];                                       // LDS broadcast
        const float2 wv = *(const float2*)(fc_w + d * D_ + 2 * lane);
        acc.x = fmaf(xv, wv.x, acc.x);
        acc.y = fmaf(xv, wv.y, acc.y);
    }
    float2 o;
    o.x = fmaxf(acc.x, 0.0f);
    o.y = fmaxf(acc.y, 0.0f);
    *(float2*)(out + (size_t)(unsigned)wid * D_ + 2 * lane) = o;
}

extern "C" void kernel_launch(void* const* d_in, const int* in_sizes, int n_in,
                              void* d_out, int out_size, void* d_ws, size_t ws_size,
                              hipStream_t stream)
{
    const int*   ids   = (const int*)d_in[0];
    const float* feats = (const float*)d_in[1];
    const int*   adj   = (const int*)d_in[2];
    const float* vc_w1 = (const float*)d_in[3];
    const float* vc_b1 = (const float*)d_in[4];
    const float* vc_w2 = (const float*)d_in[5];
    const float* vc_b2 = (const float*)d_in[6];
    const float* ec_w1 = (const float*)d_in[7];
    const float* ec_b1 = (const float*)d_in[8];
    const float* ec_w2 = (const float*)d_in[9];
    const float* ec_b2 = (const float*)d_in[10];
    const float* fc_w  = (const float*)d_in[11];
    const float* fc_b  = (const float*)d_in[12];
    float* out = (float*)d_out;

    const int n_ids   = in_sizes[0];
    const int n_total = in_sizes[1] / D_;      // feats is (n_total, 128)
    float* score1 = (float*)d_ws;              // 400 KB scratch

    dhg_score1<<<(n_total + 255) / 256, 256, 0, stream>>>(
        feats, vc_w1, vc_b1, vc_w2, vc_b2, score1, n_total);

    const int blocks = (n_ids + 1) / 2;        // 2 ids (waves) per 128-thread block
    dhg_main<<<blocks, 128, 0, stream>>>(ids, feats, adj, score1,
                                         ec_w1, ec_b1, ec_w2, ec_b2,
                                         fc_w, fc_b, out, n_ids);
}

// Round 5
// 370.017 us; speedup vs baseline: 1.4410x; 1.0410x over previous
//
#include <hip/hip_runtime.h>
#include <hip/hip_fp16.h>

// DHG layer, two-kernel scheme, fp16 gather table.
//
// R4 evidence: dhg_main duration == FETCH_SIZE / 2.47 TB/s -> pinned on L2-miss
// service BW for scattered 512B row gathers (uniform-random adj -> hit rate not
// improvable by reordering). Lever: halve miss BYTES. score1 touches every feats
// row anyway, so it emits a fp16 copy (25.6 MB) into d_ws; the pooling gather
// reads 256B/row. Scores stay fp32-exact. Also: score1 rewritten wave-per-row
// (was thread-per-row, 391 blocks, latency-bound ~123 us -> now 25K blocks,
// coalesced, ~20 us).

constexpr int S_   = 8;
constexpr int K_   = 16;
constexpr int D_   = 128;
constexpr int HVC  = 9;
constexpr int HEC  = 32;

__device__ __forceinline__ float rl_f(float v, int lane) {
    return __int_as_float(__builtin_amdgcn_readlane(__float_as_int(v), lane));
}

// ---- kernel A: wave per row. score1[n] = MLP1(feats[n]) + optional fp16 copy ----
__global__ __launch_bounds__(256)
void dhg_score1(const float* __restrict__ feats,
                const float* __restrict__ vc_w1, const float* __restrict__ vc_b1,
                const float* __restrict__ vc_w2, const float* __restrict__ vc_b2,
                float* __restrict__ score1, __half2* __restrict__ feats_h,
                int n_total)
{
    const int wave = threadIdx.x >> 6;
    const int lane = threadIdx.x & 63;
    const int n = blockIdx.x * 4 + wave;
    if (n >= n_total) return;

    // coalesced row read: lane = column pair
    const float2 v = *(const float2*)(feats + (size_t)n * D_ + 2 * lane);
    if (feats_h) feats_h[(size_t)n * 64 + lane] = __float22half2_rn(v);

    // partial h over this lane's two columns (w1 slice is per-lane, L1-hot 4.6KB)
    const float* wp = vc_w1 + (2 * lane) * HVC;
    float h[HVC];
    #pragma unroll
    for (int j = 0; j < HVC; ++j) h[j] = fmaf(v.x, wp[j], v.y * wp[HVC + j]);

    // butterfly reduce the 9 partials across 64 lanes
    #pragma unroll
    for (int j = 0; j < HVC; ++j) {
        #pragma unroll
        for (int m = 1; m <= 32; m <<= 1) h[j] += __shfl_xor(h[j], m);
    }
    float sc = vc_b2[0];
    #pragma unroll
    for (int j = 0; j < HVC; ++j)
        sc = fmaf(fmaxf(h[j] + vc_b1[j], 0.0f), vc_w2[j], sc);
    if (lane == 0) score1[n] = sc;
}

// ---- softmax weight over 16-lane groups: returns e/z for this lane ----
__device__ __forceinline__ float softmax16(float sc) {
    float mx = sc;
    #pragma unroll
    for (int m = 1; m <= 8; m <<= 1) mx = fmaxf(mx, __shfl_xor(mx, m));
    const float e = __expf(sc - mx);
    float z = e;
    #pragma unroll
    for (int m = 1; m <= 8; m <<= 1) z += __shfl_xor(z, m);
    return e / z;
}

// ---- kernel B: main fused layer, one wave per id ----
template<bool HALF>
__global__ __launch_bounds__(128, 4)
void dhg_main(const int* __restrict__ ids,
              const float* __restrict__ feats,
              const __half2* __restrict__ feats_h,
              const int* __restrict__ adj,
              const float* __restrict__ score1,
              const float* __restrict__ ec_w1, const float* __restrict__ ec_b1,
              const float* __restrict__ ec_w2, const float* __restrict__ ec_b2,
              const float* __restrict__ fc_w,  const float* __restrict__ fc_b,
              float* __restrict__ out, int n_ids)
{
    __shared__ float he_lds[2][S_ * 129];  // per-wave slice; pad 129 => broadcast conflict-free
    __shared__ float x_lds[2][D_];

    const int wave = threadIdx.x >> 6;
    const int lane = threadIdx.x & 63;
    int wid = blockIdx.x * 2 + wave;
    if (wid >= n_ids) wid = n_ids - 1;

    const int node = ids[wid];
    const int* arow = adj + (size_t)(unsigned)node * (S_ * K_);
    const int miA = arow[lane];          // hyperedges 0..3, member = lane (s=lane>>4, k=lane&15)
    const int miB = arow[lane + 64];     // hyperedges 4..7

    // precomputed scores (400 KB table, L2-resident) -> softmax weights
    const float wA = softmax16(score1[miA]);
    const float wB = softmax16(score1[miB]);

    float he_lo[S_], he_hi[S_];          // he[s][2*lane], he[s][2*lane+1]

    #pragma unroll
    for (int g = 0; g < 2; ++g) {
        const int   mi = g ? miB : miA;
        const float w  = g ? wB  : wA;
        #pragma unroll
        for (int sl = 0; sl < 4; ++sl) {
            const int s = g * 4 + sl;
            float alo = 0.0f, ahi = 0.0f;
            if constexpr (HALF) {
                __half2 fv[K_];
                #pragma unroll
                for (int k = 0; k < K_; ++k) {
                    const int mik = __builtin_amdgcn_readlane(mi, sl * 16 + k);  // SGPR row idx
                    fv[k] = feats_h[(size_t)(unsigned)mik * 64 + lane];          // 256B/row coalesced
                }
                #pragma unroll
                for (int k = 0; k < K_; ++k) {
                    const float wk = rl_f(w, sl * 16 + k);                        // SGPR weight
                    const float2 f = __half22float2(fv[k]);
                    alo = fmaf(wk, f.x, alo);
                    ahi = fmaf(wk, f.y, ahi);
                }
            } else {
                float2 fv[K_];
                #pragma unroll
                for (int k = 0; k < K_; ++k) {
                    const int mik = __builtin_amdgcn_readlane(mi, sl * 16 + k);
                    fv[k] = *(const float2*)(feats + (size_t)(unsigned)mik * D_ + 2 * lane);
                }
                #pragma unroll
                for (int k = 0; k < K_; ++k) {
                    const float wk = rl_f(w, sl * 16 + k);
                    alo = fmaf(wk, fv[k].x, alo);
                    ahi = fmaf(wk, fv[k].y, ahi);
                }
            }
            he_lo[s] = alo;
            he_hi[s] = ahi;
            he_lds[wave][s * 129 + 2 * lane]     = alo;
            he_lds[wave][s * 129 + 2 * lane + 1] = ahi;
        }
    }

    __builtin_amdgcn_wave_barrier();   // zero-cost fence: keep LDS writes before reads

    // ---- edge conv: lane = (jg = lane>>3, s8 = lane&7); j in [4*jg, 4*jg+4) ----
    const int s8 = lane & 7;
    const int jg = lane >> 3;
    const float* hrow = &he_lds[wave][s8 * 129];
    float a0 = 0.0f, a1 = 0.0f, a2 = 0.0f, a3 = 0.0f;
    #pragma unroll 4
    for (int d = 0; d < D_; ++d) {
        const float hv = hrow[d];                                     // LDS broadcast
        const float4 wv = *(const float4*)(ec_w1 + d * HEC + 4 * jg); // 16 KB, cache-hot
        a0 = fmaf(hv, wv.x, a0);
        a1 = fmaf(hv, wv.y, a1);
        a2 = fmaf(hv, wv.z, a2);
        a3 = fmaf(hv, wv.w, a3);
    }
    const float4 b4  = *(const float4*)(ec_b1 + 4 * jg);
    const float4 w24 = *(const float4*)(ec_w2 + 4 * jg);
    float p = 0.0f;
    p = fmaf(fmaxf(a0 + b4.x, 0.0f), w24.x, p);
    p = fmaf(fmaxf(a1 + b4.y, 0.0f), w24.y, p);
    p = fmaf(fmaxf(a2 + b4.z, 0.0f), w24.z, p);
    p = fmaf(fmaxf(a3 + b4.w, 0.0f), w24.w, p);
    #pragma unroll
    for (int m = 8; m <= 32; m <<= 1) p += __shfl_xor(p, m);   // reduce over jg (bits 3..5)
    const float sc2 = p + ec_b2[0];

    // softmax over 8 hyperedges (lane bits 0..2)
    float mx2 = sc2;
    #pragma unroll
    for (int m = 1; m <= 4; m <<= 1) mx2 = fmaxf(mx2, __shfl_xor(mx2, m));
    const float e2 = __expf(sc2 - mx2);
    float z2 = e2;
    #pragma unroll
    for (int m = 1; m <= 4; m <<= 1) z2 += __shfl_xor(z2, m);
    const float p2 = e2 / z2;   // lanes 0..7 hold weights for s=0..7

    // ---- x = sum_s p2[s] * he[s][:], lane = column pair (he in registers) ----
    float x_lo = 0.0f, x_hi = 0.0f;
    #pragma unroll
    for (int s = 0; s < S_; ++s) {
        const float ps = rl_f(p2, s);
        x_lo = fmaf(ps, he_lo[s], x_lo);
        x_hi = fmaf(ps, he_hi[s], x_hi);
    }
    x_lds[wave][2 * lane]     = x_lo;
    x_lds[wave][2 * lane + 1] = x_hi;

    __builtin_amdgcn_wave_barrier();   // zero-cost fence before cross-lane x_lds reads

    // ---- FC 128x128 + ReLU: lane = output column pair, fc_w L2-hot ----
    const float* xr = x_lds[wave];
    float2 acc = *(const float2*)(fc_b + 2 * lane);
    #pragma unroll 8
    for (int d = 0; d < D_; ++d) {
        const float xv = xr[d];                                       // LDS broadcast
        const float2 wv = *(const float2*)(fc_w + d * D_ + 2 * lane);
        acc.x = fmaf(xv, wv.x, acc.x);
        acc.y = fmaf(xv, wv.y, acc.y);
    }
    float2 o;
    o.x = fmaxf(acc.x, 0.0f);
    o.y = fmaxf(acc.y, 0.0f);
    *(float2*)(out + (size_t)(unsigned)wid * D_ + 2 * lane) = o;
}

extern "C" void kernel_launch(void* const* d_in, const int* in_sizes, int n_in,
                              void* d_out, int out_size, void* d_ws, size_t ws_size,
                              hipStream_t stream)
{
    const int*   ids   = (const int*)d_in[0];
    const float* feats = (const float*)d_in[1];
    const int*   adj   = (const int*)d_in[2];
    const float* vc_w1 = (const float*)d_in[3];
    const float* vc_b1 = (const float*)d_in[4];
    const float* vc_w2 = (const float*)d_in[5];
    const float* vc_b2 = (const float*)d_in[6];
    const float* ec_w1 = (const float*)d_in[7];
    const float* ec_b1 = (const float*)d_in[8];
    const float* ec_w2 = (const float*)d_in[9];
    const float* ec_b2 = (const float*)d_in[10];
    const float* fc_w  = (const float*)d_in[11];
    const float* fc_b  = (const float*)d_in[12];
    float* out = (float*)d_out;

    const int n_ids   = in_sizes[0];
    const int n_total = in_sizes[1] / D_;              // feats is (n_total, 128)

    float* score1 = (float*)d_ws;                      // 400 KB
    const size_t half_off = 512 * 1024;
    const size_t need = half_off + (size_t)n_total * 64 * sizeof(__half2);  // +25.6 MB
    __half2* feats_h = (ws_size >= need) ? (__half2*)((char*)d_ws + half_off) : nullptr;

    dhg_score1<<<(n_total + 3) / 4, 256, 0, stream>>>(
        feats, vc_w1, vc_b1, vc_w2, vc_b2, score1, feats_h, n_total);

    const int blocks = (n_ids + 1) / 2;                // 2 ids (waves) per 128-thread block
    if (feats_h)
        dhg_main<true><<<blocks, 128, 0, stream>>>(ids, feats, feats_h, adj, score1,
                                                   ec_w1, ec_b1, ec_w2, ec_b2,
                                                   fc_w, fc_b, out, n_ids);
    else
        dhg_main<false><<<blocks, 128, 0, stream>>>(ids, feats, nullptr, adj, score1,
                                                    ec_w1, ec_b1, ec_w2, ec_b2,
                                                    fc_w, fc_b, out, n_ids);
}